// Round 5
// baseline (789.588 us; speedup 1.0000x reference)
//
#include <hip/hip_runtime.h>

typedef float f32x4 __attribute__((ext_vector_type(4)));
typedef short bf16x8 __attribute__((ext_vector_type(8)));
typedef unsigned short u16;

#define LDS_STRIDE 40   // 128-row tile, 40-elem (80B) row stride: 16B-aligned
#define NEG_INF (-1e30f)

__device__ __forceinline__ u16 f2bf(float f) {
    unsigned u = __builtin_bit_cast(unsigned, f);
    unsigned r = u + 0x7FFFu + ((u >> 16) & 1u);  // RNE
    return (u16)(r >> 16);
}
__device__ __forceinline__ float bf2f(u16 h) {
    unsigned u = ((unsigned)h) << 16;
    return __builtin_bit_cast(float, u);
}

__device__ __forceinline__ float wave_max(float v) {
    #pragma unroll
    for (int o = 32; o > 0; o >>= 1) v = fmaxf(v, __shfl_xor(v, o, 64));
    return v;
}
__device__ __forceinline__ float wave_sum(float v) {
    #pragma unroll
    for (int o = 32; o > 0; o >>= 1) v += __shfl_xor(v, o, 64);
    return v;
}
__device__ __forceinline__ void wave_argmax(float& v, int& i) {
    #pragma unroll
    for (int o = 32; o > 0; o >>= 1) {
        float ov = __shfl_xor(v, o, 64);
        int oi = __shfl_xor(i, o, 64);
        if (ov > v || (ov == v && oi < i)) { v = ov; i = oi; }
    }
}

// Stage a 128x32 fp32 tile (row-major, leading dim ldK) into bf16 LDS (RNE cast in flight).
__device__ __forceinline__ void stage_tile_f32(const float* __restrict__ src, int ldK,
                                               u16* dst, int tid) {
    #pragma unroll
    for (int j = 0; j < 4; ++j) {
        int g = j * 1024 + tid * 4;
        int row = g >> 5, col = g & 31;
        float4 v = *reinterpret_cast<const float4*>(src + (size_t)row * ldK + col);
        ushort4 pk;
        pk.x = f2bf(v.x); pk.y = f2bf(v.y); pk.z = f2bf(v.z); pk.w = f2bf(v.w);
        *reinterpret_cast<ushort4*>(dst + row * LDS_STRIDE + col) = pk;
    }
}

// Stage a 128x32 bf16 tile (row-major, leading dim ldK) into LDS.
__device__ __forceinline__ void stage_tile_bf16(const u16* __restrict__ src, int ldK,
                                                u16* dst, int tid) {
    {
        int row = tid >> 2, part = tid & 3;
        uint4 v = *reinterpret_cast<const uint4*>(src + (size_t)row * ldK + part * 8);
        *reinterpret_cast<uint4*>(dst + row * LDS_STRIDE + part * 8) = v;
    }
    {
        int c = tid + 256;
        int row = c >> 2, part = c & 3;
        uint4 v = *reinterpret_cast<const uint4*>(src + (size_t)row * ldK + part * 8);
        *reinterpret_cast<uint4*>(dst + row * LDS_STRIDE + part * 8) = v;
    }
}

// A/B-frag for mfma_f32_16x16x32_bf16: lane holds [m|n = lane&15][k = (lane>>4)*8 .. +7]
__device__ __forceinline__ bf16x8 load_frag(const u16* lds, int row0, int lane) {
    int row = row0 + (lane & 15);
    int k = (lane >> 4) * 8;
    return *reinterpret_cast<const bf16x8*>(lds + row * LDS_STRIDE + k);
}

// C[N x ldC] (fp32) = A[N x K] (fp32->bf16) * B[M x K]^T (fp32->bf16). Grid: (M/128, N/128).
__global__ __launch_bounds__(256, 2) void gemm_bt_f32(
    const float* __restrict__ A, const float* __restrict__ B, float* __restrict__ C,
    int K, int ldC) {
    __shared__ u16 As[128 * LDS_STRIDE];
    __shared__ u16 Bs[128 * LDS_STRIDE];
    int tid = threadIdx.x;
    int lane = tid & 63, wave = tid >> 6;
    int rowBase = blockIdx.y * 128, colBase = blockIdx.x * 128;
    int wm = (wave >> 1) * 64, wn = (wave & 1) * 64;
    f32x4 acc[4][4] = {};
    const float* Ap = A + (size_t)rowBase * K;
    const float* Bp = B + (size_t)colBase * K;
    for (int k0 = 0; k0 < K; k0 += 32) {
        stage_tile_f32(Ap + k0, K, As, tid);
        stage_tile_f32(Bp + k0, K, Bs, tid);
        __syncthreads();
        bf16x8 af[4], bfr[4];
        #pragma unroll
        for (int i = 0; i < 4; ++i) af[i] = load_frag(As, wm + i * 16, lane);
        #pragma unroll
        for (int j = 0; j < 4; ++j) bfr[j] = load_frag(Bs, wn + j * 16, lane);
        #pragma unroll
        for (int i = 0; i < 4; ++i)
            #pragma unroll
            for (int j = 0; j < 4; ++j)
                acc[i][j] = __builtin_amdgcn_mfma_f32_16x16x32_bf16(af[i], bfr[j], acc[i][j], 0, 0, 0);
        __syncthreads();
    }
    // C/D layout: col = lane&15, row = (lane>>4)*4 + reg (verified: round-4 calibration
    // epilogue reproduced this mapping bit-identically)
    int rq = (lane >> 4) * 4, cq = lane & 15;
    #pragma unroll
    for (int i = 0; i < 4; ++i) {
        #pragma unroll
        for (int j = 0; j < 4; ++j) {
            int col = colBase + wn + j * 16 + cq;
            #pragma unroll
            for (int r = 0; r < 4; ++r) {
                int row = rowBase + wm + i * 16 + rq + r;
                C[(size_t)row * ldC + col] = acc[i][j][r];
            }
        }
    }
}

// Down GEMM + experts add: Out(fp32) = H2(bf16)*dw(fp32->bf16)^T + Out_prev(fp32 experts).
__global__ __launch_bounds__(256, 2) void gemm_down_add(
    const u16* __restrict__ A, const float* __restrict__ B, float* __restrict__ Out,
    int K, int ldC) {
    __shared__ u16 As[128 * LDS_STRIDE];
    __shared__ u16 Bs[128 * LDS_STRIDE];
    int tid = threadIdx.x;
    int lane = tid & 63, wave = tid >> 6;
    int rowBase = blockIdx.y * 128, colBase = blockIdx.x * 128;
    int wm = (wave >> 1) * 64, wn = (wave & 1) * 64;
    f32x4 acc[4][4] = {};
    const u16* Ap = A + (size_t)rowBase * K;
    const float* Bp = B + (size_t)colBase * K;
    for (int k0 = 0; k0 < K; k0 += 32) {
        stage_tile_bf16(Ap + k0, K, As, tid);
        stage_tile_f32(Bp + k0, K, Bs, tid);
        __syncthreads();
        bf16x8 af[4], bfr[4];
        #pragma unroll
        for (int i = 0; i < 4; ++i) af[i] = load_frag(As, wm + i * 16, lane);
        #pragma unroll
        for (int j = 0; j < 4; ++j) bfr[j] = load_frag(Bs, wn + j * 16, lane);
        #pragma unroll
        for (int i = 0; i < 4; ++i)
            #pragma unroll
            for (int j = 0; j < 4; ++j)
                acc[i][j] = __builtin_amdgcn_mfma_f32_16x16x32_bf16(af[i], bfr[j], acc[i][j], 0, 0, 0);
        __syncthreads();
    }
    int rq = (lane >> 4) * 4, cq = lane & 15;
    #pragma unroll
    for (int i = 0; i < 4; ++i) {
        #pragma unroll
        for (int j = 0; j < 4; ++j) {
            int col = colBase + wn + j * 16 + cq;
            #pragma unroll
            for (int r = 0; r < 4; ++r) {
                int row = rowBase + wm + i * 16 + rq + r;
                size_t o = (size_t)row * ldC + col;
                Out[o] = acc[i][j][r] + Out[o];   // add experts term (same-thread RMW)
            }
        }
    }
}

// Fused gate/up GEMM: H2[rows x 4096] (bf16) = silu(x*Wg^T) * (x*Wu^T); fp32 in.
__global__ __launch_bounds__(256, 2) void gemm_gateup(
    const float* __restrict__ A, const float* __restrict__ Wg, const float* __restrict__ Wu,
    u16* __restrict__ H2, int K, int ldH) {
    __shared__ u16 As[128 * LDS_STRIDE];
    __shared__ u16 Gs[128 * LDS_STRIDE];
    __shared__ u16 Us[128 * LDS_STRIDE];
    int tid = threadIdx.x;
    int lane = tid & 63, wave = tid >> 6;
    int rowBase = blockIdx.y * 128, colBase = blockIdx.x * 128;
    int wm = (wave >> 1) * 64, wn = (wave & 1) * 64;
    f32x4 accg[4][4] = {}, accu[4][4] = {};
    const float* Ap = A + (size_t)rowBase * K;
    const float* Gp = Wg + (size_t)colBase * K;
    const float* Up = Wu + (size_t)colBase * K;
    for (int k0 = 0; k0 < K; k0 += 32) {
        stage_tile_f32(Ap + k0, K, As, tid);
        stage_tile_f32(Gp + k0, K, Gs, tid);
        stage_tile_f32(Up + k0, K, Us, tid);
        __syncthreads();
        bf16x8 af[4], gfr[4], ufr[4];
        #pragma unroll
        for (int i = 0; i < 4; ++i) af[i] = load_frag(As, wm + i * 16, lane);
        #pragma unroll
        for (int j = 0; j < 4; ++j) gfr[j] = load_frag(Gs, wn + j * 16, lane);
        #pragma unroll
        for (int j = 0; j < 4; ++j) ufr[j] = load_frag(Us, wn + j * 16, lane);
        #pragma unroll
        for (int i = 0; i < 4; ++i) {
            #pragma unroll
            for (int j = 0; j < 4; ++j) {
                accg[i][j] = __builtin_amdgcn_mfma_f32_16x16x32_bf16(af[i], gfr[j], accg[i][j], 0, 0, 0);
                accu[i][j] = __builtin_amdgcn_mfma_f32_16x16x32_bf16(af[i], ufr[j], accu[i][j], 0, 0, 0);
            }
        }
        __syncthreads();
    }
    int rq = (lane >> 4) * 4, cq = lane & 15;
    #pragma unroll
    for (int i = 0; i < 4; ++i) {
        #pragma unroll
        for (int j = 0; j < 4; ++j) {
            int col = colBase + wn + j * 16 + cq;
            #pragma unroll
            for (int r = 0; r < 4; ++r) {
                int row = rowBase + wm + i * 16 + rq + r;
                float g = accg[i][j][r], u = accu[i][j][r];
                float h = (g / (1.f + __expf(-g))) * u;   // silu(g)*u
                H2[(size_t)row * ldH + col] = f2bf(h);
            }
        }
    }
}

// Column sums / sum-of-squares of R[4096 x 256] into stats[0..255]=sum, [256..511]=sumsq.
__global__ void bn_stats(const float* __restrict__ R, float* __restrict__ stats) {
    int c = threadIdx.x;
    int r0 = blockIdx.x * 256;
    float s = 0.f, s2 = 0.f;
    for (int r = r0; r < r0 + 256; ++r) {
        float v = R[(size_t)r * 256 + c];
        s += v; s2 += v * v;
    }
    atomicAdd(&stats[c], s);
    atomicAdd(&stats[256 + c], s2);
}

// Per-token (1 wave): batchnorm -> log_softmax(x cols 0..127, y cols 128..255) ->
// top16(lpx), top16(lpy) -> top16 of 256 candidate sums (dominance lemma).
__global__ __launch_bounds__(64) void router_topk(
    const float* __restrict__ R, const float* __restrict__ stats,
    int* __restrict__ idx_out, float* __restrict__ wt_out) {
    int n = blockIdx.x, lane = threadIdx.x;
    const float invN = 1.0f / 4096.0f;
    float z[4];
    #pragma unroll
    for (int p = 0; p < 4; ++p) {
        int c = p * 64 + lane;
        float mean = stats[c] * invN;
        float var = fmaxf(stats[256 + c] * invN - mean * mean, 0.f);  // biased var
        float v = R[(size_t)n * 256 + c];
        z[p] = (v - mean) * rsqrtf(var + 1e-5f);
    }
    float mx = wave_max(fmaxf(z[0], z[1]));
    float sx = __logf(wave_sum(__expf(z[0] - mx) + __expf(z[1] - mx)));
    float lx0 = z[0] - mx - sx, lx1 = z[1] - mx - sx;
    float my = wave_max(fmaxf(z[2], z[3]));
    float sy = __logf(wave_sum(__expf(z[2] - my) + __expf(z[3] - my)));
    float ly0 = z[2] - my - sy, ly1 = z[3] - my - sy;

    __shared__ float tx[16], ty[16];
    __shared__ int txc[16], tyc[16];
    float v0 = lx0, v1 = lx1;
    for (int t = 0; t < 16; ++t) {
        float bv; int bc;
        if (v1 > v0) { bv = v1; bc = lane + 64; } else { bv = v0; bc = lane; }
        wave_argmax(bv, bc);
        if (lane == 0) { tx[t] = bv; txc[t] = bc; }
        if (bc == lane) v0 = NEG_INF;
        else if (bc == lane + 64) v1 = NEG_INF;
    }
    v0 = ly0; v1 = ly1;
    for (int t = 0; t < 16; ++t) {
        float bv; int bc;
        if (v1 > v0) { bv = v1; bc = lane + 64; } else { bv = v0; bc = lane; }
        wave_argmax(bv, bc);
        if (lane == 0) { ty[t] = bv; tyc[t] = bc; }
        if (bc == lane) v0 = NEG_INF;
        else if (bc == lane + 64) v1 = NEG_INF;
    }
    __syncthreads();
    float cv[4]; int ci[4];
    #pragma unroll
    for (int p = 0; p < 4; ++p) {
        int pid = p * 64 + lane;
        cv[p] = tx[pid >> 4] + ty[pid & 15];
        ci[p] = pid;
    }
    for (int t = 0; t < 16; ++t) {
        float bv = cv[0]; int bc = ci[0];
        #pragma unroll
        for (int p = 1; p < 4; ++p)
            if (cv[p] > bv) { bv = cv[p]; bc = ci[p]; }
        wave_argmax(bv, bc);
        if (lane == 0) {
            idx_out[n * 16 + t] = txc[bc >> 4] * 128 + tyc[bc & 15];
            wt_out[n * 16 + t] = __expf(bv);
        }
        #pragma unroll
        for (int p = 0; p < 4; ++p)
            if (ci[p] == bc) cv[p] = NEG_INF;
    }
}

// Per-token block: 16 expert dots, silu*weight, weighted combine of down_embed rows;
// writes ONLY the experts term (fp32) into Out.
__global__ __launch_bounds__(256) void expert_store(
    const float* __restrict__ X, const float* __restrict__ UE, const float* __restrict__ DE,
    const int* __restrict__ idxs, const float* __restrict__ wts, float* __restrict__ Out) {
    int n = blockIdx.x, tid = threadIdx.x;
    int lane = tid & 63, wave = tid >> 6;
    __shared__ float xs[1024];
    __shared__ float ews[16];
    __shared__ int sidx[16];
    __shared__ float swt[16];
    if (tid < 16) {
        sidx[tid] = min(max(idxs[n * 16 + tid], 0), 16383);  // clamp: no wild gathers
        swt[tid] = wts[n * 16 + tid];
    }
    {
        float4 v = reinterpret_cast<const float4*>(X + (size_t)n * 1024)[tid];
        *reinterpret_cast<float4*>(xs + tid * 4) = v;
    }
    __syncthreads();
    #pragma unroll
    for (int q = 0; q < 4; ++q) {
        int e = wave * 4 + q;
        const float* row = UE + (size_t)sidx[e] * 1024;
        float acc = 0.f;
        #pragma unroll
        for (int c = 0; c < 4; ++c) {
            int h = c * 256 + lane * 4;
            float4 a = *reinterpret_cast<const float4*>(row + h);
            float4 xv = *reinterpret_cast<const float4*>(xs + h);
            acc += a.x * xv.x + a.y * xv.y + a.z * xv.z + a.w * xv.w;
        }
        acc = wave_sum(acc);
        if (lane == 0) {
            float s = acc / (1.f + __expf(-acc));   // silu
            ews[e] = s * swt[e];
        }
    }
    __syncthreads();
    float4 a = make_float4(0.f, 0.f, 0.f, 0.f);
    int h = tid * 4;
    #pragma unroll
    for (int e = 0; e < 16; ++e) {
        const float* row = DE + (size_t)sidx[e] * 1024;
        float4 v = *reinterpret_cast<const float4*>(row + h);
        float w = ews[e];
        a.x += w * v.x; a.y += w * v.y;
        a.z += w * v.z; a.w += w * v.w;
    }
    reinterpret_cast<float4*>(Out + (size_t)n * 1024)[tid] = a;
}

extern "C" void kernel_launch(void* const* d_in, const int* in_sizes, int n_in,
                              void* d_out, int out_size, void* d_ws, size_t ws_size,
                              hipStream_t stream) {
    // fp32 inputs AND fp32 output (reference computes fp32 end-to-end; round-3/4
    // absmax 2.125 == pair-packing artifact of writing bf16 into an fp32 buffer).
    const float* x   = (const float*)d_in[0];   // [4096,1024]
    const float* gw  = (const float*)d_in[1];   // [4096,1024]
    const float* uw  = (const float*)d_in[2];   // [4096,1024]
    const float* dw  = (const float*)d_in[3];   // [1024,4096]
    const float* rxw = (const float*)d_in[4];   // [128,1024]
    const float* ryw = (const float*)d_in[5];   // [128,1024]
    const float* ue  = (const float*)d_in[6];   // [16384,1024]
    const float* de  = (const float*)d_in[7];   // [16384,1024]
    float* out = (float*)d_out;                 // [4096,1024] fp32

    // Workspace: stats(16KB pad) + idx(256KB) + wt(256KB) + R(4MB) + H2 chunk.
    char* p = (char*)d_ws;
    float* stats = (float*)p; p += 16384;
    int*   idxb  = (int*)p;   p += (size_t)4096 * 16 * 4;
    float* wtb   = (float*)p; p += (size_t)4096 * 16 * 4;
    float* R     = (float*)p; p += (size_t)4096 * 256 * 4;
    u16*   H2    = (u16*)p;   // chunked: chunkTokens*4096 bf16
    size_t fixed = (size_t)(p - (char*)d_ws);

    // Pick dense-MLP chunking from ws_size (host-visible): H2 chunk must fit.
    int chunkTokens;
    if (ws_size >= fixed + (size_t)4096 * 4096 * 2)      chunkTokens = 4096;  // 32 MB H2
    else if (ws_size >= fixed + (size_t)512 * 4096 * 2)  chunkTokens = 512;   // 4 MB
    else                                                 chunkTokens = 128;   // 1 MB
    int nch = 4096 / chunkTokens;

    hipMemsetAsync(stats, 0, 512 * sizeof(float), stream);

    dim3 blk(256);
    gemm_bt_f32<<<dim3(1, 32), blk, 0, stream>>>(x, rxw, R, 1024, 256);        // R[:,0:128]
    gemm_bt_f32<<<dim3(1, 32), blk, 0, stream>>>(x, ryw, R + 128, 1024, 256);  // R[:,128:256]
    bn_stats<<<16, 256, 0, stream>>>(R, stats);
    router_topk<<<4096, 64, 0, stream>>>(R, stats, idxb, wtb);
    expert_store<<<4096, blk, 0, stream>>>(x, ue, de, idxb, wtb, out);         // experts -> out

    for (int c = 0; c < nch; ++c) {
        const float* xc = x + (size_t)c * chunkTokens * 1024;
        float* outc = out + (size_t)c * chunkTokens * 1024;
        gemm_gateup<<<dim3(32, chunkTokens / 128), blk, 0, stream>>>(xc, gw, uw, H2, 1024, 4096);
        gemm_down_add<<<dim3(8, chunkTokens / 128), blk, 0, stream>>>(H2, dw, outc, 4096, 1024);
    }
}